// Round 4
// baseline (933.419 us; speedup 1.0000x reference)
//
#include <hip/hip_runtime.h>

// SeparableConv3D fused: x[8,3,32,256,256] fp32, depthwise K=5 cross-corr
// along W, H, T, zero 'same' padding.
//
// v5: wave-autonomous zero-barrier (v4 structure) + CONFLICT-FREE LDS.
// v4's stride-68 float4 reads were the bottleneck (40M conflict cycles).
// Fix: store each staged x-row TWICE as dense 64-float arrays
//   A[row] = x[e 0..64)   B[row] = x[e 4..68)    (e = col - (w0-2))
// so both H-conv operand reads become F = const + 4*ln — the canonical
// lane-contiguous ds_read_b128 pattern (wave reads 1 KB contiguous),
// conflict-free by construction, with a single vaddr + imm offsets.
// Duplication is paid at write time: each loaded float2 is written to its
// A-slot and B-slot (invalid -> per-lane dump strip, branch-free).
//
// Single LDS buffer per wave: DS ops of one wave execute in order, so
// read(slice t) -> write(slice t+1) -> read(slice t+1) is hazard-free
// without barriers. 2-deep register prefetch (pA/pB) as in v4.
//
// Traffic: ~220 MB read + 201 MB write -> ~67 us floor @ 6.3 TB/s.

#define N_  8
#define C_  3
#define T_  32
#define H_  256
#define W_  256
#define K_  5
#define HW_ (H_ * W_)

#define TH 16          // block output rows (4 waves x 4)
#define TW 64          // block output cols

// Per-wave LDS region (floats): A[8][64] | B[8][64] | dump[128]
#define ABASE 0
#define BBASE 512
#define DBASE 1024
#define REG_F 1152     // 4608 B per wave

typedef float nfloat4 __attribute__((ext_vector_type(4)));

__global__ __launch_bounds__(256, 6)
void sep3d_wave5(const float* __restrict__ x,
                 const float* __restrict__ w1,
                 const float* __restrict__ w2,
                 const float* __restrict__ w3,
                 float* __restrict__ out)
{
    __shared__ __align__(16) float sxAll[4][REG_F];   // 18432 B

    const int tid = threadIdx.x;
    const int wv  = tid >> 6;
    const int ln  = tid & 63;
    const int nc  = blockIdx.z;             // n*C + c
    const int c   = nc % C_;
    const int h0  = blockIdx.y * TH + wv * 4;   // wave's first output row
    const int w0  = blockIdx.x * TW;

    const float* xnc = x   + (size_t)nc * (T_ * HW_);
    float*       onc = out + (size_t)nc * (T_ * HW_);

    float k1[K_], k2[K_], k3[K_];
#pragma unroll
    for (int k = 0; k < K_; ++k) {
        k1[k] = w1[c * K_ + k];
        k2[k] = w2[c * K_ + k];
        k3[k] = w3[c * K_ + k];
    }

    float* base = &sxAll[wv][0];

    // ---- Staging descriptors (t-invariant): 272 float2 tasks / 64 lanes ----
    // Task i: row = i/34 (0..7), e = 2*(i%34) (0..66); covers x cols
    // [w0-2, w0+66) of rows [h0-2, h0+6).
    int  goff[5];
    bool gok[5];
    int  loffA[5], loffB[5];
#pragma unroll
    for (int j = 0; j < 5; ++j) {
        int i    = ln + 64 * j;             // [0, 320)
        int row  = i / 34;
        int c2   = i - row * 34;
        int e    = 2 * c2;                  // [0, 66]
        int gh   = h0 - 2 + row;
        int gw   = w0 - 2 + e;
        bool valid = (i < 272);
        gok[j]   = valid && ((unsigned)gh < H_) && (gw >= 0) && (gw + 1 < W_);
        goff[j]  = gok[j] ? (gh * W_ + gw) : 0;
        int lr   = row * 64 + e;
        int dmp  = DBASE + 2 * ln;          // per-lane dump slot (conflict-free)
        loffA[j] = (valid && e <= 62) ? (ABASE + lr)     : dmp;
        loffB[j] = (valid && e >= 4)  ? (BBASE + lr - 4) : dmp;
    }

    // ---- Compute-task constants: 1 output float4 per lane ----
    const int r0 = ln >> 4;                 // 0..3 : output row within strip
    const int s3 = ln & 15;                 // 0..15: 4-col segment
    float* gst = onc + (size_t)(h0 + r0) * W_ + (w0 + 4 * s3);
    const float* rd = base + 4 * ln;        // A-read base; B at +BBASE

    // T-conv register ring: at start of iter t,
    // a0=partial out(t-2), a1=out(t-1), a2=out(t), a3=out(t+1).
    nfloat4 a0 = {0,0,0,0}, a1 = a0, a2 = a0, a3 = a0;

    float2 pA[5], pB[5];

#define LOADP(P, tt) do {                                                   \
    const int tc_ = ((tt) < T_) ? (tt) : 0;                                 \
    const bool tok_ = (tt) < T_;                                            \
    const float* xt_ = xnc + (size_t)tc_ * HW_;                             \
    _Pragma("unroll") for (int j = 0; j < 5; ++j) {                         \
        float2 v_ = *(const float2*)(xt_ + goff[j]);                        \
        bool ok_ = tok_ && gok[j];                                          \
        (P)[j].x = ok_ ? v_.x : 0.0f;                                       \
        (P)[j].y = ok_ ? v_.y : 0.0f;                                       \
    } } while (0)

    // Write slice data to both A and B images (dump strip absorbs edges).
#define WRITEP(P) do {                                                      \
    _Pragma("unroll") for (int j = 0; j < 5; ++j) {                         \
        *(float2*)(base + loffA[j]) = (P)[j];                               \
        *(float2*)(base + loffB[j]) = (P)[j];                               \
    } } while (0)

    // Fused W+H conv from LDS (slice tt), T-ring update + store.
#define COMPUTE(tt) do {                                                    \
    nfloat4 z = {0,0,0,0};                                                  \
    _Pragma("unroll") for (int k = 0; k < K_; ++k) {                        \
        float4 aa = *(const float4*)(rd + 64 * k);                          \
        float4 bb = *(const float4*)(rd + BBASE + 64 * k);                  \
        float y0 = aa.x*k1[0]+aa.y*k1[1]+aa.z*k1[2]+aa.w*k1[3]+bb.x*k1[4];  \
        float y1 = aa.y*k1[0]+aa.z*k1[1]+aa.w*k1[2]+bb.x*k1[3]+bb.y*k1[4];  \
        float y2 = aa.z*k1[0]+aa.w*k1[1]+bb.x*k1[2]+bb.y*k1[3]+bb.z*k1[4];  \
        float y3 = aa.w*k1[0]+bb.x*k1[1]+bb.y*k1[2]+bb.z*k1[3]+bb.w*k1[4];  \
        z.x += y0 * k2[k]; z.y += y1 * k2[k];                               \
        z.z += y2 * k2[k]; z.w += y3 * k2[k];                               \
    }                                                                       \
    nfloat4 dn;                                                             \
    dn.x = a0.x + z.x * k3[4]; dn.y = a0.y + z.y * k3[4];                   \
    dn.z = a0.z + z.z * k3[4]; dn.w = a0.w + z.w * k3[4];                   \
    if ((tt) >= 2)                                                          \
        __builtin_nontemporal_store(dn,                                     \
            (nfloat4*)(gst + (size_t)((tt) - 2) * HW_));                    \
    a0.x = a1.x + z.x * k3[3]; a0.y = a1.y + z.y * k3[3];                   \
    a0.z = a1.z + z.z * k3[3]; a0.w = a1.w + z.w * k3[3];                   \
    a1.x = a2.x + z.x * k3[2]; a1.y = a2.y + z.y * k3[2];                   \
    a1.z = a2.z + z.z * k3[2]; a1.w = a2.w + z.w * k3[2];                   \
    a2.x = a3.x + z.x * k3[1]; a2.y = a3.y + z.y * k3[1];                   \
    a2.z = a3.z + z.z * k3[1]; a2.w = a3.w + z.w * k3[1];                   \
    a3.x = z.x * k3[0]; a3.y = z.y * k3[0];                                 \
    a3.z = z.z * k3[0]; a3.w = z.w * k3[0];                                 \
    } while (0)

    // ---- Prologue: slice 0 -> LDS; prefetch slices 1 (pA) and 2 (pB) ----
    LOADP(pA, 0);
    WRITEP(pA);
    LOADP(pA, 1);
    LOADP(pB, 2);

    // ---- Main loop: single LDS buffer, in-order DS pipe = no hazards ----
    for (int t = 0; t < T_; t += 2) {
        COMPUTE(t);             // reads slice t
        WRITEP(pA);             // slice t+1 -> LDS (after reads, in order)
        LOADP(pA, t + 3);       // in flight ~1 full t-iteration
        COMPUTE(t + 1);         // reads slice t+1
        WRITEP(pB);             // slice t+2 -> LDS
        LOADP(pB, t + 4);
    }

    // Epilogue: out(30) = a0, out(31) = a1 (z beyond T is zero padding)
    __builtin_nontemporal_store(a0, (nfloat4*)(gst + (size_t)30 * HW_));
    __builtin_nontemporal_store(a1, (nfloat4*)(gst + (size_t)31 * HW_));

#undef LOADP
#undef WRITEP
#undef COMPUTE
}

extern "C" void kernel_launch(void* const* d_in, const int* in_sizes, int n_in,
                              void* d_out, int out_size, void* d_ws, size_t ws_size,
                              hipStream_t stream)
{
    const float* x  = (const float*)d_in[0];
    const float* w1 = (const float*)d_in[1];
    const float* w2 = (const float*)d_in[2];
    const float* w3 = (const float*)d_in[3];
    float* out = (float*)d_out;

    dim3 grid(W_ / TW, H_ / TH, N_ * C_);   // 4 x 16 x 24 = 1536 blocks
    sep3d_wave5<<<grid, 256, 0, stream>>>(x, w1, w2, w3, out);
}

// Round 5
// 370.975 us; speedup vs baseline: 2.5161x; 2.5161x over previous
//
#include <hip/hip_runtime.h>

// SeparableConv3D fused: x[8,3,32,256,256] fp32, depthwise K=5 cross-corr
// along W, H, T, zero 'same' padding.
//
// v6 = v5 minus the __launch_bounds__ min-waves clause. v5's ",6" handed
// the allocator a ~40-VGPR budget -> ~60 VGPRs of prefetch/descriptor
// state spilled to scratch (+2.2 GB HBM traffic, 712 us). The v5 LDS
// theory itself verified: bank conflicts 40.2M -> 9.6M.
//
// Structure: wave-autonomous, ZERO barriers. Each wave owns a 4x64 output
// strip for all t; stages its own 8-row x 68-col halo slice into a private
// single LDS buffer, stored TWICE as dense images
//   A[row] = x[e 0..64)   B[row] = x[e 4..68)
// so both W-conv operand reads are F = const + 4*ln (lane-contiguous
// ds_read_b128, conflict-free, single vaddr + imm offsets). Per-wave DS
// in-order execution makes read(t) -> write(t+1) -> read(t+1) safe with
// no barrier. 2-deep register prefetch (pA/pB) hides HBM latency.
//
// Traffic: ~220 MB read + 201 MB write -> ~67 us floor @ 6.3 TB/s.

#define N_  8
#define C_  3
#define T_  32
#define H_  256
#define W_  256
#define K_  5
#define HW_ (H_ * W_)

#define TH 16          // block output rows (4 waves x 4)
#define TW 64          // block output cols

// Per-wave LDS region (floats): A[8][64] | B[8][64] | dump[128]
#define ABASE 0
#define BBASE 512
#define DBASE 1024
#define REG_F 1152     // 4608 B per wave

typedef float nfloat4 __attribute__((ext_vector_type(4)));

__global__ __launch_bounds__(256)
void sep3d_wave6(const float* __restrict__ x,
                 const float* __restrict__ w1,
                 const float* __restrict__ w2,
                 const float* __restrict__ w3,
                 float* __restrict__ out)
{
    __shared__ __align__(16) float sxAll[4][REG_F];   // 18432 B

    const int tid = threadIdx.x;
    const int wv  = tid >> 6;
    const int ln  = tid & 63;
    const int nc  = blockIdx.z;             // n*C + c
    const int c   = nc % C_;
    const int h0  = blockIdx.y * TH + wv * 4;   // wave's first output row
    const int w0  = blockIdx.x * TW;

    const float* xnc = x   + (size_t)nc * (T_ * HW_);
    float*       onc = out + (size_t)nc * (T_ * HW_);

    float k1[K_], k2[K_], k3[K_];
#pragma unroll
    for (int k = 0; k < K_; ++k) {
        k1[k] = w1[c * K_ + k];
        k2[k] = w2[c * K_ + k];
        k3[k] = w3[c * K_ + k];
    }

    float* base = &sxAll[wv][0];

    // ---- Staging descriptors (t-invariant): 272 float2 tasks / 64 lanes ----
    // Task i: row = i/34 (0..7), e = 2*(i%34) (0..66); covers x cols
    // [w0-2, w0+66) of rows [h0-2, h0+6).
    int  goff[5];
    bool gok[5];
    int  loffA[5], loffB[5];
#pragma unroll
    for (int j = 0; j < 5; ++j) {
        int i    = ln + 64 * j;             // [0, 320)
        int row  = i / 34;
        int c2   = i - row * 34;
        int e    = 2 * c2;                  // [0, 66]
        int gh   = h0 - 2 + row;
        int gw   = w0 - 2 + e;
        bool valid = (i < 272);
        gok[j]   = valid && ((unsigned)gh < H_) && (gw >= 0) && (gw + 1 < W_);
        goff[j]  = gok[j] ? (gh * W_ + gw) : 0;
        int lr   = row * 64 + e;
        int dmp  = DBASE + 2 * ln;          // per-lane dump slot (conflict-free)
        loffA[j] = (valid && e <= 62) ? (ABASE + lr)     : dmp;
        loffB[j] = (valid && e >= 4)  ? (BBASE + lr - 4) : dmp;
    }

    // ---- Compute-task constants: 1 output float4 per lane ----
    const int r0 = ln >> 4;                 // 0..3 : output row within strip
    const int s3 = ln & 15;                 // 0..15: 4-col segment
    float* gst = onc + (size_t)(h0 + r0) * W_ + (w0 + 4 * s3);
    const float* rd = base + 4 * ln;        // A-read base; B at +BBASE

    // T-conv register ring: at start of iter t,
    // a0=partial out(t-2), a1=out(t-1), a2=out(t), a3=out(t+1).
    nfloat4 a0 = {0,0,0,0}, a1 = a0, a2 = a0, a3 = a0;

    float2 pA[5], pB[5];

#define LOADP(P, tt) do {                                                   \
    const int tc_ = ((tt) < T_) ? (tt) : 0;                                 \
    const bool tok_ = (tt) < T_;                                            \
    const float* xt_ = xnc + (size_t)tc_ * HW_;                             \
    _Pragma("unroll") for (int j = 0; j < 5; ++j) {                         \
        float2 v_ = *(const float2*)(xt_ + goff[j]);                        \
        bool ok_ = tok_ && gok[j];                                          \
        (P)[j].x = ok_ ? v_.x : 0.0f;                                       \
        (P)[j].y = ok_ ? v_.y : 0.0f;                                       \
    } } while (0)

    // Write slice data to both A and B images (dump strip absorbs edges).
#define WRITEP(P) do {                                                      \
    _Pragma("unroll") for (int j = 0; j < 5; ++j) {                         \
        *(float2*)(base + loffA[j]) = (P)[j];                               \
        *(float2*)(base + loffB[j]) = (P)[j];                               \
    } } while (0)

    // Fused W+H conv from LDS (slice tt), T-ring update + store.
#define COMPUTE(tt) do {                                                    \
    nfloat4 z = {0,0,0,0};                                                  \
    _Pragma("unroll") for (int k = 0; k < K_; ++k) {                        \
        float4 aa = *(const float4*)(rd + 64 * k);                          \
        float4 bb = *(const float4*)(rd + BBASE + 64 * k);                  \
        float y0 = aa.x*k1[0]+aa.y*k1[1]+aa.z*k1[2]+aa.w*k1[3]+bb.x*k1[4];  \
        float y1 = aa.y*k1[0]+aa.z*k1[1]+aa.w*k1[2]+bb.x*k1[3]+bb.y*k1[4];  \
        float y2 = aa.z*k1[0]+aa.w*k1[1]+bb.x*k1[2]+bb.y*k1[3]+bb.z*k1[4];  \
        float y3 = aa.w*k1[0]+bb.x*k1[1]+bb.y*k1[2]+bb.z*k1[3]+bb.w*k1[4];  \
        z.x += y0 * k2[k]; z.y += y1 * k2[k];                               \
        z.z += y2 * k2[k]; z.w += y3 * k2[k];                               \
    }                                                                       \
    nfloat4 dn;                                                             \
    dn.x = a0.x + z.x * k3[4]; dn.y = a0.y + z.y * k3[4];                   \
    dn.z = a0.z + z.z * k3[4]; dn.w = a0.w + z.w * k3[4];                   \
    if ((tt) >= 2)                                                          \
        __builtin_nontemporal_store(dn,                                     \
            (nfloat4*)(gst + (size_t)((tt) - 2) * HW_));                    \
    a0.x = a1.x + z.x * k3[3]; a0.y = a1.y + z.y * k3[3];                   \
    a0.z = a1.z + z.z * k3[3]; a0.w = a1.w + z.w * k3[3];                   \
    a1.x = a2.x + z.x * k3[2]; a1.y = a2.y + z.y * k3[2];                   \
    a1.z = a2.z + z.z * k3[2]; a1.w = a2.w + z.w * k3[2];                   \
    a2.x = a3.x + z.x * k3[1]; a2.y = a3.y + z.y * k3[1];                   \
    a2.z = a3.z + z.z * k3[1]; a2.w = a3.w + z.w * k3[1];                   \
    a3.x = z.x * k3[0]; a3.y = z.y * k3[0];                                 \
    a3.z = z.z * k3[0]; a3.w = z.w * k3[0];                                 \
    } while (0)

    // ---- Prologue: slice 0 -> LDS; prefetch slices 1 (pA) and 2 (pB) ----
    LOADP(pA, 0);
    WRITEP(pA);
    LOADP(pA, 1);
    LOADP(pB, 2);

    // ---- Main loop: single LDS buffer, in-order DS pipe = no hazards ----
    for (int t = 0; t < T_; t += 2) {
        COMPUTE(t);             // reads slice t
        WRITEP(pA);             // slice t+1 -> LDS (after reads, in order)
        LOADP(pA, t + 3);       // in flight ~1 full t-iteration
        COMPUTE(t + 1);         // reads slice t+1
        WRITEP(pB);             // slice t+2 -> LDS
        LOADP(pB, t + 4);
    }

    // Epilogue: out(30) = a0, out(31) = a1 (z beyond T is zero padding)
    __builtin_nontemporal_store(a0, (nfloat4*)(gst + (size_t)30 * HW_));
    __builtin_nontemporal_store(a1, (nfloat4*)(gst + (size_t)31 * HW_));

#undef LOADP
#undef WRITEP
#undef COMPUTE
}

extern "C" void kernel_launch(void* const* d_in, const int* in_sizes, int n_in,
                              void* d_out, int out_size, void* d_ws, size_t ws_size,
                              hipStream_t stream)
{
    const float* x  = (const float*)d_in[0];
    const float* w1 = (const float*)d_in[1];
    const float* w2 = (const float*)d_in[2];
    const float* w3 = (const float*)d_in[3];
    float* out = (float*)d_out;

    dim3 grid(W_ / TW, H_ / TH, N_ * C_);   // 4 x 16 x 24 = 1536 blocks
    sep3d_wave6<<<grid, 256, 0, stream>>>(x, w1, w2, w3, out);
}